// Round 1
// baseline (118.832 us; speedup 1.0000x reference)
//
#include <hip/hip_runtime.h>

// Problem constants (fixed by reference file)
#define IMG 224
#define WS 8
#define STRIDE 2
#define NP 109                 // (224-8)/2+1 patches per dimension
#define BC 48                  // batch*channels = 16*3
#define NPIX (IMG * IMG)       // 50176
#define NPATCH (NP * NP)       // 11881

// The filter _gen_filter(2,16,8) zeros exactly coefficients (0,0),(0,1),(1,0)
// (s>16 never fires for 8x8). D is orthonormal DCT-II, so per patch:
//   y = P - Xd00*D0(x)D0 - Xd01*D0(x)D1 - Xd10*D1(x)D0
// We read (1-filt) at those 3 positions from device so the weights are live.

// ---------------- Kernel 1: per-patch low-frequency coefficients --------------
__global__ __launch_bounds__(256) void patch_coef_kernel(
    const float* __restrict__ x, const float* __restrict__ D,
    const float* __restrict__ filt,
    float* __restrict__ c00p, float* __restrict__ c01p, float* __restrict__ c10p)
{
    int idx = blockIdx.x * blockDim.x + threadIdx.x;
    if (idx >= BC * NPATCH) return;
    int bc  = idx / NPATCH;
    int rem = idx - bc * NPATCH;
    int pr  = rem / NP;
    int pc  = rem - pr * NP;

    float D0[8], D1[8];
#pragma unroll
    for (int j = 0; j < 8; ++j) { D0[j] = D[j]; D1[j] = D[8 + j]; }

    const float* base = x + (size_t)bc * NPIX + (size_t)(pr * STRIDE) * IMG + (pc * STRIDE);
    float c00 = 0.f, c01 = 0.f, c10 = 0.f;
#pragma unroll
    for (int i = 0; i < 8; ++i) {
        const float2* row = (const float2*)(base + (size_t)i * IMG);  // 8B-aligned (even col)
        float s = 0.f, t = 0.f;
#pragma unroll
        for (int j2 = 0; j2 < 4; ++j2) {
            float2 v = row[j2];
            s = fmaf(v.x, D0[2 * j2], fmaf(v.y, D0[2 * j2 + 1], s));
            t = fmaf(v.x, D1[2 * j2], fmaf(v.y, D1[2 * j2 + 1], t));
        }
        c00 = fmaf(D0[i], s, c00);
        c01 = fmaf(D0[i], t, c01);
        c10 = fmaf(D1[i], s, c10);
    }
    // weight by (1 - filt) at the killed positions
    c00 *= (1.0f - filt[0]);       // filt[0][0]
    c01 *= (1.0f - filt[1]);       // filt[0][1]
    c10 *= (1.0f - filt[8]);       // filt[1][0]
    c00p[idx] = c00;
    c01p[idx] = c01;
    c10p[idx] = c10;
}

// ---------------- Kernel 2: gather per output pixel ---------------------------
__global__ __launch_bounds__(256) void gather_kernel(
    const float* __restrict__ x, const float* __restrict__ D,
    const float* __restrict__ c00p, const float* __restrict__ c01p,
    const float* __restrict__ c10p, float* __restrict__ out)
{
    int idx = blockIdx.x * blockDim.x + threadIdx.x;
    if (idx >= BC * NPIX) return;
    int bc  = idx / NPIX;
    int rem = idx - bc * NPIX;
    int h   = rem / IMG;
    int w   = rem - h * IMG;

    float D0[8], D1[8];
#pragma unroll
    for (int j = 0; j < 8; ++j) { D0[j] = D[j]; D1[j] = D[8 + j]; }

    int pr_lo = (h >= 6) ? ((h - 6) >> 1) : 0;   // ceil((h-7)/2) clipped at 0
    int pr_hi = min(NP - 1, h >> 1);
    int pc_lo = (w >= 6) ? ((w - 6) >> 1) : 0;
    int pc_hi = min(NP - 1, w >> 1);

    const float* c00b = c00p + (size_t)bc * NPATCH;
    const float* c01b = c01p + (size_t)bc * NPATCH;
    const float* c10b = c10p + (size_t)bc * NPATCH;

    float acc = 0.f;
    for (int pr = pr_lo; pr <= pr_hi; ++pr) {
        int i = h - STRIDE * pr;
        float d0i = D0[i], d1i = D1[i];
        int rowoff = pr * NP;
        for (int pc = pc_lo; pc <= pc_hi; ++pc) {
            int j = w - STRIDE * pc;
            int o = rowoff + pc;
            float a = c00b[o], b = c01b[o], c = c10b[o];
            acc = fmaf(d0i, fmaf(a, D0[j], b * D1[j]), fmaf(d1i, c * D0[j], acc));
        }
    }
    float cnt = (float)((pr_hi - pr_lo + 1) * (pc_hi - pc_lo + 1));
    out[idx] = cnt * x[idx] - acc;
}

// ---------------- Fallback: direct per-pixel (only if ws too small) ----------
__global__ __launch_bounds__(256) void direct_kernel(
    const float* __restrict__ x, const float* __restrict__ D,
    const float* __restrict__ filt, float* __restrict__ out)
{
    int idx = blockIdx.x * blockDim.x + threadIdx.x;
    if (idx >= BC * NPIX) return;
    int bc  = idx / NPIX;
    int rem = idx - bc * NPIX;
    int h   = rem / IMG;
    int w   = rem - h * IMG;

    float D0[8], D1[8];
#pragma unroll
    for (int j = 0; j < 8; ++j) { D0[j] = D[j]; D1[j] = D[8 + j]; }
    float w00 = 1.0f - filt[0], w01 = 1.0f - filt[1], w10 = 1.0f - filt[8];

    int pr_lo = (h >= 6) ? ((h - 6) >> 1) : 0;
    int pr_hi = min(NP - 1, h >> 1);
    int pc_lo = (w >= 6) ? ((w - 6) >> 1) : 0;
    int pc_hi = min(NP - 1, w >> 1);

    const float* xbc = x + (size_t)bc * NPIX;
    float acc = 0.f;
    for (int pr = pr_lo; pr <= pr_hi; ++pr) {
        int i = h - STRIDE * pr;
        float d0i = D0[i], d1i = D1[i];
        for (int pc = pc_lo; pc <= pc_hi; ++pc) {
            int j = w - STRIDE * pc;
            const float* base = xbc + (size_t)(pr * STRIDE) * IMG + (pc * STRIDE);
            float c00 = 0.f, c01 = 0.f, c10 = 0.f;
            for (int ii = 0; ii < 8; ++ii) {
                float s = 0.f, t = 0.f;
                for (int jj = 0; jj < 8; ++jj) {
                    float v = base[(size_t)ii * IMG + jj];
                    s = fmaf(v, D0[jj], s);
                    t = fmaf(v, D1[jj], t);
                }
                c00 = fmaf(D0[ii], s, c00);
                c01 = fmaf(D0[ii], t, c01);
                c10 = fmaf(D1[ii], s, c10);
            }
            c00 *= w00; c01 *= w01; c10 *= w10;
            acc = fmaf(d0i, fmaf(c00, D0[j], c01 * D1[j]), fmaf(d1i, c10 * D0[j], acc));
        }
    }
    float cnt = (float)((pr_hi - pr_lo + 1) * (pc_hi - pc_lo + 1));
    out[idx] = cnt * x[idx] - acc;
}

extern "C" void kernel_launch(void* const* d_in, const int* in_sizes, int n_in,
                              void* d_out, int out_size, void* d_ws, size_t ws_size,
                              hipStream_t stream)
{
    const float* x    = (const float*)d_in[0];
    const float* D    = (const float*)d_in[1];
    const float* filt = (const float*)d_in[2];
    float* out        = (float*)d_out;

    const size_t plane = (size_t)BC * NPATCH;            // 570288 floats
    const size_t need  = 3 * plane * sizeof(float);      // ~6.85 MB

    if (ws_size >= need) {
        float* c00p = (float*)d_ws;
        float* c01p = c00p + plane;
        float* c10p = c01p + plane;

        int npatch_tot = BC * NPATCH;
        patch_coef_kernel<<<(npatch_tot + 255) / 256, 256, 0, stream>>>(
            x, D, filt, c00p, c01p, c10p);

        int npix_tot = BC * NPIX;
        gather_kernel<<<(npix_tot + 255) / 256, 256, 0, stream>>>(
            x, D, c00p, c01p, c10p, out);
    } else {
        int npix_tot = BC * NPIX;
        direct_kernel<<<(npix_tot + 255) / 256, 256, 0, stream>>>(x, D, filt, out);
    }
}

// Round 2
// 83.190 us; speedup vs baseline: 1.4284x; 1.4284x over previous
//
#include <hip/hip_runtime.h>

// Problem constants (fixed by reference file)
#define IMG 224
#define WS 8
#define STRIDE 2
#define NP 109                 // (224-8)/2+1 patches per dimension
#define BC 48                  // batch*channels = 16*3
#define NPIX (IMG * IMG)       // 50176
#define NPATCH (NP * NP)       // 11881
#define NQ 112                 // quads per dimension (IMG/2)
#define NQP (NQ * NQ)          // 12544

// filt zeros exactly coefficients (0,0),(0,1),(1,0); D orthonormal =>
//   y = P - c00*D0(x)D0 - c01*D0(x)D1 - c10*D1(x)D0   per patch,
// and the scatter-add of P over patches is cnt(h,w)*x[h,w].
//
// CODEGEN RULE learned in R1: never index a private float[8] with a runtime
// value -- SROA fails, the array lands in scratch, and every access becomes a
// hidden global load (gather v1: ~1900 instr/pixel, VGPR=24). All D accesses
// below are literal-indexed named scalars via macro unrolling.

#define LOAD_D_SCALARS(D)                                                  \
    const float d0_0 = (D)[0], d0_1 = (D)[1], d0_2 = (D)[2], d0_3 = (D)[3],\
                d0_4 = (D)[4], d0_5 = (D)[5], d0_6 = (D)[6], d0_7 = (D)[7];\
    const float d1_0 = (D)[8],  d1_1 = (D)[9],  d1_2 = (D)[10],            \
                d1_3 = (D)[11], d1_4 = (D)[12], d1_5 = (D)[13],            \
                d1_6 = (D)[14], d1_7 = (D)[15];

// ---------------- Kernel 1: per-patch low-frequency coefficients -------------
__global__ __launch_bounds__(256) void patch_coef_kernel(
    const float* __restrict__ x, const float* __restrict__ D,
    const float* __restrict__ filt,
    float2* __restrict__ cab, float* __restrict__ cc)
{
    int idx = blockIdx.x * blockDim.x + threadIdx.x;
    if (idx >= BC * NPATCH) return;
    int bc  = idx / NPATCH;
    int rem = idx - bc * NPATCH;
    int pr  = rem / NP;
    int pc  = rem - pr * NP;

    LOAD_D_SCALARS(D)

    const float* base = x + (size_t)bc * NPIX + (size_t)(pr * STRIDE) * IMG + (pc * STRIDE);
    float c00 = 0.f, c01 = 0.f, c10 = 0.f;

#define K1_ROW(i)                                                              \
    {                                                                          \
        const float2* row = (const float2*)(base + (size_t)(i) * IMG);         \
        float2 v0 = row[0], v1 = row[1], v2 = row[2], v3 = row[3];             \
        float s = fmaf(v0.x, d0_0, fmaf(v0.y, d0_1,                            \
                  fmaf(v1.x, d0_2, fmaf(v1.y, d0_3,                            \
                  fmaf(v2.x, d0_4, fmaf(v2.y, d0_5,                            \
                  fmaf(v3.x, d0_6, v3.y * d0_7)))))));                         \
        float t = fmaf(v0.x, d1_0, fmaf(v0.y, d1_1,                            \
                  fmaf(v1.x, d1_2, fmaf(v1.y, d1_3,                            \
                  fmaf(v2.x, d1_4, fmaf(v2.y, d1_5,                            \
                  fmaf(v3.x, d1_6, v3.y * d1_7)))))));                         \
        c00 = fmaf(d0_##i, s, c00);                                            \
        c01 = fmaf(d0_##i, t, c01);                                            \
        c10 = fmaf(d1_##i, s, c10);                                            \
    }

    K1_ROW(0) K1_ROW(1) K1_ROW(2) K1_ROW(3)
    K1_ROW(4) K1_ROW(5) K1_ROW(6) K1_ROW(7)
#undef K1_ROW

    float w00 = 1.0f - filt[0];   // filt[0][0]
    float w01 = 1.0f - filt[1];   // filt[0][1]
    float w10 = 1.0f - filt[8];   // filt[1][0]
    cab[idx] = make_float2(c00 * w00, c01 * w01);
    cc[idx]  = c10 * w10;
}

// ---------------- Kernel 2: gather, one thread per 2x2 output quad -----------
// Even/odd pixel pairs share the identical patch window, so with a quad the
// DCT-row indices i,j are compile-time constants: i = 6-2*kr (+1 odd row),
// j = 6-2*kc (+1 odd col).
__global__ __launch_bounds__(256) void gather2_kernel(
    const float* __restrict__ x, const float* __restrict__ D,
    const float2* __restrict__ cab, const float* __restrict__ cc,
    float* __restrict__ out)
{
    int idx = blockIdx.x * blockDim.x + threadIdx.x;
    if (idx >= BC * NQP) return;
    int bc  = idx / NQP;
    int rem = idx - bc * NQP;
    int qh  = rem / NQ;
    int qw  = rem - qh * NQ;

    LOAD_D_SCALARS(D)

    const float2* cabb = cab + (size_t)bc * NPATCH;
    const float*  ccb  = cc  + (size_t)bc * NPATCH;

    const int prb = qh - 3;
    const int pcb = qw - 3;

    float aee = 0.f, aeo = 0.f, aoe = 0.f, aoo = 0.f;

#define G_COL(kc, je, jo)                                                      \
    {                                                                          \
        int pc = pcb + (kc);                                                   \
        if (pc >= 0 && pc < NP) {                                              \
            int o = rowoff + pc;                                               \
            float2 ab = cabb[o];                                               \
            float  cv = ccb[o];                                                \
            Se = fmaf(ab.x, d0_##je, fmaf(ab.y, d1_##je, Se));                 \
            So = fmaf(ab.x, d0_##jo, fmaf(ab.y, d1_##jo, So));                 \
            Te = fmaf(cv, d0_##je, Te);                                        \
            To = fmaf(cv, d0_##jo, To);                                        \
        }                                                                      \
    }

#define G_ROW(kr, ie, io)                                                      \
    {                                                                          \
        int pr = prb + (kr);                                                   \
        if (pr >= 0 && pr < NP) {                                              \
            int rowoff = pr * NP;                                              \
            float Se = 0.f, So = 0.f, Te = 0.f, To = 0.f;                      \
            G_COL(0, 6, 7) G_COL(1, 4, 5) G_COL(2, 2, 3) G_COL(3, 0, 1)        \
            aee = fmaf(d0_##ie, Se, fmaf(d1_##ie, Te, aee));                   \
            aeo = fmaf(d0_##ie, So, fmaf(d1_##ie, To, aeo));                   \
            aoe = fmaf(d0_##io, Se, fmaf(d1_##io, Te, aoe));                   \
            aoo = fmaf(d0_##io, So, fmaf(d1_##io, To, aoo));                   \
        }                                                                      \
    }

    G_ROW(0, 6, 7) G_ROW(1, 4, 5) G_ROW(2, 2, 3) G_ROW(3, 0, 1)
#undef G_ROW
#undef G_COL

    int nvr = min(qh, NP - 1) - max(prb, 0) + 1;
    int nvc = min(qw, NP - 1) - max(pcb, 0) + 1;
    float cnt = (float)(nvr * nvc);

    int h0 = 2 * qh, w0 = 2 * qw;
    const float* xr = x   + (size_t)bc * NPIX + (size_t)h0 * IMG + w0;
    float*       orp = out + (size_t)bc * NPIX + (size_t)h0 * IMG + w0;
    float2 x0 = *(const float2*)xr;
    float2 x1 = *(const float2*)(xr + IMG);
    float2 o0, o1;
    o0.x = fmaf(cnt, x0.x, -aee);
    o0.y = fmaf(cnt, x0.y, -aeo);
    o1.x = fmaf(cnt, x1.x, -aoe);
    o1.y = fmaf(cnt, x1.y, -aoo);
    *(float2*)orp         = o0;
    *(float2*)(orp + IMG) = o1;
}

// ---------------- Fallback: direct per-pixel (only if ws too small) ----------
__global__ __launch_bounds__(256) void direct_kernel(
    const float* __restrict__ x, const float* __restrict__ D,
    const float* __restrict__ filt, float* __restrict__ out)
{
    int idx = blockIdx.x * blockDim.x + threadIdx.x;
    if (idx >= BC * NPIX) return;
    int bc  = idx / NPIX;
    int rem = idx - bc * NPIX;
    int h   = rem / IMG;
    int w   = rem - h * IMG;

    float D0[8], D1[8];
#pragma unroll
    for (int j = 0; j < 8; ++j) { D0[j] = D[j]; D1[j] = D[8 + j]; }
    float w00 = 1.0f - filt[0], w01 = 1.0f - filt[1], w10 = 1.0f - filt[8];

    int pr_lo = (h >= 6) ? ((h - 6) >> 1) : 0;
    int pr_hi = min(NP - 1, h >> 1);
    int pc_lo = (w >= 6) ? ((w - 6) >> 1) : 0;
    int pc_hi = min(NP - 1, w >> 1);

    const float* xbc = x + (size_t)bc * NPIX;
    float acc = 0.f;
    for (int pr = pr_lo; pr <= pr_hi; ++pr) {
        int i = h - STRIDE * pr;
        float d0i = D0[i], d1i = D1[i];
        for (int pc = pc_lo; pc <= pc_hi; ++pc) {
            int j = w - STRIDE * pc;
            const float* base = xbc + (size_t)(pr * STRIDE) * IMG + (pc * STRIDE);
            float c00 = 0.f, c01 = 0.f, c10 = 0.f;
            for (int ii = 0; ii < 8; ++ii) {
                float s = 0.f, t = 0.f;
                for (int jj = 0; jj < 8; ++jj) {
                    float v = base[(size_t)ii * IMG + jj];
                    s = fmaf(v, D0[jj], s);
                    t = fmaf(v, D1[jj], t);
                }
                c00 = fmaf(D0[ii], s, c00);
                c01 = fmaf(D0[ii], t, c01);
                c10 = fmaf(D1[ii], s, c10);
            }
            c00 *= w00; c01 *= w01; c10 *= w10;
            acc = fmaf(d0i, fmaf(c00, D0[j], c01 * D1[j]), fmaf(d1i, c10 * D0[j], acc));
        }
    }
    float cnt = (float)((pr_hi - pr_lo + 1) * (pc_hi - pc_lo + 1));
    out[idx] = cnt * x[idx] - acc;
}

extern "C" void kernel_launch(void* const* d_in, const int* in_sizes, int n_in,
                              void* d_out, int out_size, void* d_ws, size_t ws_size,
                              hipStream_t stream)
{
    const float* x    = (const float*)d_in[0];
    const float* D    = (const float*)d_in[1];
    const float* filt = (const float*)d_in[2];
    float* out        = (float*)d_out;

    const size_t plane = (size_t)BC * NPATCH;                       // 570288
    const size_t need  = plane * (sizeof(float2) + sizeof(float));  // ~6.85 MB

    if (ws_size >= need) {
        float2* cab = (float2*)d_ws;
        float*  cc  = (float*)(cab + plane);

        int npatch_tot = BC * NPATCH;
        patch_coef_kernel<<<(npatch_tot + 255) / 256, 256, 0, stream>>>(
            x, D, filt, cab, cc);

        int nquad_tot = BC * NQP;
        gather2_kernel<<<(nquad_tot + 255) / 256, 256, 0, stream>>>(
            x, D, cab, cc, out);
    } else {
        int npix_tot = BC * NPIX;
        direct_kernel<<<(npix_tot + 255) / 256, 256, 0, stream>>>(x, D, filt, out);
    }
}

// Round 3
// 77.508 us; speedup vs baseline: 1.5332x; 1.0733x over previous
//
#include <hip/hip_runtime.h>

// Problem constants (fixed by reference file)
#define IMG 224
#define NP 109                 // (224-8)/2+1 patches per dimension
#define BC 48                  // batch*channels = 16*3
#define NPIX (IMG * IMG)       // 50176
#define TILE 56                // output pixels per tile side (224 = 4*56)
#define QT 28                  // 2x2 quads per tile side
#define PT 31                  // patch rows/cols relevant to one tile
#define XR 68                  // staged x-region side (56 + 6 halo + 6 over)
#define XC2 34                 // float2 columns in x-region

// Math: filt zeros DCT coefficients (0,0),(0,1),(1,0) only; D orthonormal =>
// per-patch y = P - c00*D0(x)D0 - c01*D0(x)D1 - c10*D1(x)D0, and the
// scatter-add of P collapses to cnt(h,w)*x[h,w]. Fully fused per-tile:
// stage x -> patch coefs (invalid patches = 0 => branch-free gather) -> quads.
//
// CODEGEN RULE (R1): no runtime-indexed private arrays -- D lives in named
// scalars, all loops macro-unrolled with literal indices. LDS indexing with
// runtime values is fine (real ds_read, not scratch).

#define LOAD_D_SCALARS(D)                                                  \
    const float d0_0 = (D)[0], d0_1 = (D)[1], d0_2 = (D)[2], d0_3 = (D)[3],\
                d0_4 = (D)[4], d0_5 = (D)[5], d0_6 = (D)[6], d0_7 = (D)[7];\
    const float d1_0 = (D)[8],  d1_1 = (D)[9],  d1_2 = (D)[10],            \
                d1_3 = (D)[11], d1_4 = (D)[12], d1_5 = (D)[13],            \
                d1_6 = (D)[14], d1_7 = (D)[15];

__global__ __launch_bounds__(256) void fused_dct_kernel(
    const float* __restrict__ x, const float* __restrict__ D,
    const float* __restrict__ filt, float* __restrict__ out)
{
    __shared__ float x_s[XR * XR];         // 18.5 KB
    __shared__ float ca_s[PT * PT];        // 3 x 3.84 KB
    __shared__ float cb_s[PT * PT];
    __shared__ float cc_s[PT * PT];

    const int tid = threadIdx.x;
    const int h0 = blockIdx.y * TILE;
    const int w0 = blockIdx.x * TILE;
    const int bc = blockIdx.z;

    LOAD_D_SCALARS(D)
    const float w00 = 1.0f - filt[0];      // filt[0][0]
    const float w01 = 1.0f - filt[1];      // filt[0][1]
    const float w10 = 1.0f - filt[8];      // filt[1][0]

    const float* xb = x + (size_t)bc * NPIX;

    // ---- Phase 1: stage x region rows/cols [h0-6, h0+61] into LDS, OOB -> 0
    for (int i = tid; i < XR * XC2; i += 256) {
        int r  = i / XC2;
        int c2 = i - r * XC2;
        int gr = h0 - 6 + r;
        int gc = w0 - 6 + 2 * c2;          // even => float2-aligned
        float2 v = make_float2(0.f, 0.f);
        if ((unsigned)gr < (unsigned)IMG && (unsigned)gc < (unsigned)IMG)
            v = *(const float2*)(xb + (size_t)gr * IMG + gc);
        *(float2*)&x_s[r * XR + 2 * c2] = v;   // XR even => aligned
    }
    __syncthreads();

    // ---- Phase 2: 31x31 patch coefficients (invalid patches stored as 0)
    const int pr0 = (h0 >> 1) - 3;
    const int pc0 = (w0 >> 1) - 3;
    for (int p = tid; p < PT * PT; p += 256) {
        int prl = p / PT;
        int pcl = p - prl * PT;
        const float* wnd = &x_s[(2 * prl) * XR + 2 * pcl];
        float c00 = 0.f, c01 = 0.f, c10 = 0.f;

#define C_ROW(i)                                                               \
        {                                                                      \
            const float2* prow = (const float2*)(wnd + (i) * XR);              \
            float2 v0 = prow[0], v1 = prow[1], v2 = prow[2], v3 = prow[3];     \
            float s = fmaf(v0.x, d0_0, fmaf(v0.y, d0_1,                        \
                      fmaf(v1.x, d0_2, fmaf(v1.y, d0_3,                        \
                      fmaf(v2.x, d0_4, fmaf(v2.y, d0_5,                        \
                      fmaf(v3.x, d0_6, v3.y * d0_7)))))));                     \
            float t = fmaf(v0.x, d1_0, fmaf(v0.y, d1_1,                        \
                      fmaf(v1.x, d1_2, fmaf(v1.y, d1_3,                        \
                      fmaf(v2.x, d1_4, fmaf(v2.y, d1_5,                        \
                      fmaf(v3.x, d1_6, v3.y * d1_7)))))));                     \
            c00 = fmaf(d0_##i, s, c00);                                        \
            c01 = fmaf(d0_##i, t, c01);                                        \
            c10 = fmaf(d1_##i, s, c10);                                        \
        }

        C_ROW(0) C_ROW(1) C_ROW(2) C_ROW(3)
        C_ROW(4) C_ROW(5) C_ROW(6) C_ROW(7)
#undef C_ROW

        bool valid = ((unsigned)(pr0 + prl) < (unsigned)NP) &&
                     ((unsigned)(pc0 + pcl) < (unsigned)NP);
        float m = valid ? 1.0f : 0.0f;
        ca_s[p] = c00 * w00 * m;
        cb_s[p] = c01 * w01 * m;
        cc_s[p] = c10 * w10 * m;
    }
    __syncthreads();

    // ---- Phase 3: branch-free gather, one 2x2 output quad per iteration
    const int qh0 = h0 >> 1, qw0 = w0 >> 1;
    float* ob = out + (size_t)bc * NPIX;
    for (int q = tid; q < QT * QT; q += 256) {
        int qhl = q / QT;
        int qwl = q - qhl * QT;

        float aee = 0.f, aeo = 0.f, aoe = 0.f, aoo = 0.f;

#define G_COL(kc, je, jo)                                                      \
        {                                                                      \
            int o = ro + (kc);                                                 \
            float a = ca_s[o], b = cb_s[o], c = cc_s[o];                       \
            Se = fmaf(a, d0_##je, fmaf(b, d1_##je, Se));                       \
            So = fmaf(a, d0_##jo, fmaf(b, d1_##jo, So));                       \
            Te = fmaf(c, d0_##je, Te);                                         \
            To = fmaf(c, d0_##jo, To);                                         \
        }

#define G_ROW(kr, ie, io)                                                      \
        {                                                                      \
            int ro = (qhl + (kr)) * PT + qwl;                                  \
            float Se = 0.f, So = 0.f, Te = 0.f, To = 0.f;                      \
            G_COL(0, 6, 7) G_COL(1, 4, 5) G_COL(2, 2, 3) G_COL(3, 0, 1)        \
            aee = fmaf(d0_##ie, Se, fmaf(d1_##ie, Te, aee));                   \
            aeo = fmaf(d0_##ie, So, fmaf(d1_##ie, To, aeo));                   \
            aoe = fmaf(d0_##io, Se, fmaf(d1_##io, Te, aoe));                   \
            aoo = fmaf(d0_##io, So, fmaf(d1_##io, To, aoo));                   \
        }

        G_ROW(0, 6, 7) G_ROW(1, 4, 5) G_ROW(2, 2, 3) G_ROW(3, 0, 1)
#undef G_ROW
#undef G_COL

        int qh = qh0 + qhl, qw = qw0 + qwl;
        int nvr = min(qh, NP - 1) - max(qh - 3, 0) + 1;
        int nvc = min(qw, NP - 1) - max(qw - 3, 0) + 1;
        float cnt = (float)(nvr * nvc);

        int lr = 2 * qhl + 6, lc = 2 * qwl + 6;       // x_s coords of quad
        float2 x0 = *(const float2*)&x_s[lr * XR + lc];
        float2 x1 = *(const float2*)&x_s[(lr + 1) * XR + lc];

        float2 o0, o1;
        o0.x = fmaf(cnt, x0.x, -aee);
        o0.y = fmaf(cnt, x0.y, -aeo);
        o1.x = fmaf(cnt, x1.x, -aoe);
        o1.y = fmaf(cnt, x1.y, -aoo);

        float* orp = ob + (size_t)(h0 + 2 * qhl) * IMG + (w0 + 2 * qwl);
        *(float2*)orp         = o0;
        *(float2*)(orp + IMG) = o1;
    }
}

extern "C" void kernel_launch(void* const* d_in, const int* in_sizes, int n_in,
                              void* d_out, int out_size, void* d_ws, size_t ws_size,
                              hipStream_t stream)
{
    const float* x    = (const float*)d_in[0];
    const float* D    = (const float*)d_in[1];
    const float* filt = (const float*)d_in[2];
    float* out        = (float*)d_out;

    dim3 grid(IMG / TILE, IMG / TILE, BC);   // 4 x 4 x 48 = 768 workgroups
    fused_dct_kernel<<<grid, 256, 0, stream>>>(x, D, filt, out);
    (void)d_ws; (void)ws_size;               // workspace intentionally unused
}

// Round 4
// 73.859 us; speedup vs baseline: 1.6089x; 1.0494x over previous
//
#include <hip/hip_runtime.h>

// Problem constants (fixed by reference file)
#define IMG 224
#define NP 109                 // (224-8)/2+1 patches per dimension
#define BC 48                  // batch*channels = 16*3
#define NPIX (IMG * IMG)       // 50176
#define TILE 56                // output pixels per tile side (224 = 4*56)
#define QT 28                  // 2x2 quads per tile side
#define PT 31                  // patch rows/cols relevant to one tile
#define XR 68                  // staged x-region rows (56 + 6 halo + 6 over)
#define XC2 34                 // de-interleaved columns (float2 halves)

// Math: filt zeros DCT coefficients (0,0),(0,1),(1,0) only; D orthonormal =>
// per-patch y = P - c00*D0(x)D0 - c01*D0(x)D1 - c10*D1(x)D0, and the
// scatter-add of P collapses to cnt(h,w)*x[h,w].
//
// R4 structure (separable, shared partials):
//   P1 stage x de-interleaved (xe=even cols, xo=odd cols)   [global->LDS]
//   P2 row partials  s(r,pc)=D0.row, t(r,pc)=D1.row         (68x31, shared 4x)
//   P3 patch coefs   c00,c01,c10 from s,t                   (31x31)
//   P4 row-gather    RSe/RSo/RTe/RTo(pr,qw)                 (31x28, shared 4x)
//   P5 quads: combine 4 row-gathers + identity term         (28x28)
// All LDS reads stride-1 b32 (conflict-free). RS* overlays dead s/t buffer.
//
// CODEGEN RULE (R1): no runtime-indexed private arrays -- all D accesses are
// literal-indexed named scalars via macro unrolling.

#define LOAD_D_SCALARS(D)                                                  \
    const float d0_0 = (D)[0], d0_1 = (D)[1], d0_2 = (D)[2], d0_3 = (D)[3],\
                d0_4 = (D)[4], d0_5 = (D)[5], d0_6 = (D)[6], d0_7 = (D)[7];\
    const float d1_0 = (D)[8],  d1_1 = (D)[9],  d1_2 = (D)[10],            \
                d1_3 = (D)[11], d1_4 = (D)[12], d1_5 = (D)[13],            \
                d1_6 = (D)[14], d1_7 = (D)[15];

// LDS layout (floats)
#define O_XE   0                       // 68*34 = 2312
#define O_XO   (O_XE + XR * XC2)       // 2312
#define O_RS   (O_XO + XR * XC2)       // 68*31 = 2108
#define O_RT   (O_RS + XR * PT)        // 2108
#define O_RSE  O_RS                    // overlays RS/RT after P3 (868 each)
#define O_RSO  (O_RSE + PT * QT)
#define O_RTE  (O_RSO + PT * QT)
#define O_RTO  (O_RTE + PT * QT)
#define O_CA   (O_RT + XR * PT)        // 31*31 = 961
#define O_CB   (O_CA + PT * PT)
#define O_CC   (O_CB + PT * PT)
#define LDS_FLOATS (O_CC + PT * PT)    // 11723 floats = 46.9 KB

__global__ __launch_bounds__(256) void fused_dct_kernel(
    const float* __restrict__ x, const float* __restrict__ D,
    const float* __restrict__ filt, float* __restrict__ out)
{
    __shared__ float lds[LDS_FLOATS];
    float* const xe_s = lds + O_XE;
    float* const xo_s = lds + O_XO;
    float* const rs_s = lds + O_RS;
    float* const rt_s = lds + O_RT;
    float* const ca_s = lds + O_CA;
    float* const cb_s = lds + O_CB;
    float* const cc_s = lds + O_CC;
    float* const RSe  = lds + O_RSE;
    float* const RSo  = lds + O_RSO;
    float* const RTe  = lds + O_RTE;
    float* const RTo  = lds + O_RTO;

    const int tid = threadIdx.x;
    const int h0 = blockIdx.y * TILE;
    const int w0 = blockIdx.x * TILE;
    const int bc = blockIdx.z;

    LOAD_D_SCALARS(D)
    const float w00 = 1.0f - filt[0];      // filt[0][0]
    const float w01 = 1.0f - filt[1];      // filt[0][1]
    const float w10 = 1.0f - filt[8];      // filt[1][0]

    const float* xb = x + (size_t)bc * NPIX;

    // ---- P1: stage x rows [h0-6, h0+61], cols [w0-6, w0+61], de-interleaved
    for (int i = tid; i < XR * XC2; i += 256) {
        int r  = i / XC2;
        int c2 = i - r * XC2;
        int gr = h0 - 6 + r;
        int gc = w0 - 6 + 2 * c2;              // even => float2-aligned
        float2 v = make_float2(0.f, 0.f);
        if ((unsigned)gr < (unsigned)IMG && (unsigned)gc < (unsigned)IMG)
            v = *(const float2*)(xb + (size_t)gr * IMG + gc);
        xe_s[r * XC2 + c2] = v.x;
        xo_s[r * XC2 + c2] = v.y;
    }
    __syncthreads();

    // ---- P2: row partials s(r,pc) = D0 . xrow, t(r,pc) = D1 . xrow
    for (int i = tid; i < XR * PT; i += 256) {
        int r  = i / PT;
        int pc = i - r * PT;
        int b  = r * XC2 + pc;
        float e0 = xe_s[b],     o0 = xo_s[b];
        float e1 = xe_s[b + 1], o1 = xo_s[b + 1];
        float e2 = xe_s[b + 2], o2 = xo_s[b + 2];
        float e3 = xe_s[b + 3], o3 = xo_s[b + 3];
        float s = fmaf(e0, d0_0, fmaf(o0, d0_1,
                  fmaf(e1, d0_2, fmaf(o1, d0_3,
                  fmaf(e2, d0_4, fmaf(o2, d0_5,
                  fmaf(e3, d0_6, o3 * d0_7)))))));
        float t = fmaf(e0, d1_0, fmaf(o0, d1_1,
                  fmaf(e1, d1_2, fmaf(o1, d1_3,
                  fmaf(e2, d1_4, fmaf(o2, d1_5,
                  fmaf(e3, d1_6, o3 * d1_7)))))));
        rs_s[i] = s;
        rt_s[i] = t;
    }
    __syncthreads();

    // ---- P3: patch coefficients (invalid patches -> 0)
    const int pr0 = (h0 >> 1) - 3;
    const int pc0 = (w0 >> 1) - 3;
    for (int p = tid; p < PT * PT; p += 256) {
        int prl = p / PT;
        int pcl = p - prl * PT;
        int b   = (2 * prl) * PT + pcl;
        float c00 = 0.f, c01 = 0.f, c10 = 0.f;
#define P3_ROW(i)                                                              \
        {                                                                      \
            float s = rs_s[b + (i) * PT];                                      \
            float t = rt_s[b + (i) * PT];                                      \
            c00 = fmaf(d0_##i, s, c00);                                        \
            c01 = fmaf(d0_##i, t, c01);                                        \
            c10 = fmaf(d1_##i, s, c10);                                        \
        }
        P3_ROW(0) P3_ROW(1) P3_ROW(2) P3_ROW(3)
        P3_ROW(4) P3_ROW(5) P3_ROW(6) P3_ROW(7)
#undef P3_ROW
        bool valid = ((unsigned)(pr0 + prl) < (unsigned)NP) &&
                     ((unsigned)(pc0 + pcl) < (unsigned)NP);
        float m = valid ? 1.0f : 0.0f;
        ca_s[p] = c00 * w00 * m;
        cb_s[p] = c01 * w01 * m;
        cc_s[p] = c10 * w10 * m;
    }
    __syncthreads();   // also protects RS* overlay of rs/rt

    // ---- P4: row-gather partials over patch columns (shared by 4 quads)
    for (int i = tid; i < PT * QT; i += 256) {
        int pr = i / QT;
        int qw = i - pr * QT;
        int b  = pr * PT + qw;
        float se = 0.f, so = 0.f, te = 0.f, to = 0.f;
#define P4_COL(kc, je, jo)                                                     \
        {                                                                      \
            float a = ca_s[b + (kc)];                                          \
            float bb = cb_s[b + (kc)];                                         \
            float c = cc_s[b + (kc)];                                          \
            se = fmaf(a, d0_##je, fmaf(bb, d1_##je, se));                      \
            so = fmaf(a, d0_##jo, fmaf(bb, d1_##jo, so));                      \
            te = fmaf(c, d0_##je, te);                                         \
            to = fmaf(c, d0_##jo, to);                                         \
        }
        P4_COL(0, 6, 7) P4_COL(1, 4, 5) P4_COL(2, 2, 3) P4_COL(3, 0, 1)
#undef P4_COL
        RSe[i] = se; RSo[i] = so; RTe[i] = te; RTo[i] = to;
    }
    __syncthreads();

    // ---- P5: quads — combine 4 row partials + identity term
    const int qh0 = h0 >> 1, qw0 = w0 >> 1;
    float* ob = out + (size_t)bc * NPIX;
    for (int q = tid; q < QT * QT; q += 256) {
        int qhl = q / QT;
        int qwl = q - qhl * QT;
        int b   = qhl * QT + qwl;
        float aee = 0.f, aeo = 0.f, aoe = 0.f, aoo = 0.f;
#define P5_ROW(kr, ie, io)                                                     \
        {                                                                      \
            int o = b + (kr) * QT;                                             \
            float se = RSe[o], so = RSo[o], te = RTe[o], to = RTo[o];          \
            aee = fmaf(d0_##ie, se, fmaf(d1_##ie, te, aee));                   \
            aeo = fmaf(d0_##ie, so, fmaf(d1_##ie, to, aeo));                   \
            aoe = fmaf(d0_##io, se, fmaf(d1_##io, te, aoe));                   \
            aoo = fmaf(d0_##io, so, fmaf(d1_##io, to, aoo));                   \
        }
        P5_ROW(0, 6, 7) P5_ROW(1, 4, 5) P5_ROW(2, 2, 3) P5_ROW(3, 0, 1)
#undef P5_ROW

        int qh = qh0 + qhl, qw = qw0 + qwl;
        int nvr = min(qh, NP - 1) - max(qh - 3, 0) + 1;
        int nvc = min(qw, NP - 1) - max(qw - 3, 0) + 1;
        float cnt = (float)(nvr * nvc);

        // identity term: quad pixels at staged rows 2qhl+6, cols 2qwl+6
        int xr = (2 * qhl + 6) * XC2 + (qwl + 3);
        float x00 = xe_s[xr],       x01 = xo_s[xr];
        float x10 = xe_s[xr + XC2], x11 = xo_s[xr + XC2];

        float2 o0, o1;
        o0.x = fmaf(cnt, x00, -aee);
        o0.y = fmaf(cnt, x01, -aeo);
        o1.x = fmaf(cnt, x10, -aoe);
        o1.y = fmaf(cnt, x11, -aoo);

        float* orp = ob + (size_t)(h0 + 2 * qhl) * IMG + (w0 + 2 * qwl);
        *(float2*)orp         = o0;
        *(float2*)(orp + IMG) = o1;
    }
}

extern "C" void kernel_launch(void* const* d_in, const int* in_sizes, int n_in,
                              void* d_out, int out_size, void* d_ws, size_t ws_size,
                              hipStream_t stream)
{
    const float* x    = (const float*)d_in[0];
    const float* D    = (const float*)d_in[1];
    const float* filt = (const float*)d_in[2];
    float* out        = (float*)d_out;

    dim3 grid(IMG / TILE, IMG / TILE, BC);   // 4 x 4 x 48 = 768 workgroups
    fused_dct_kernel<<<grid, 256, 0, stream>>>(x, D, filt, out);
    (void)d_ws; (void)ws_size;               // workspace intentionally unused
}